// Round 9
// baseline (322.388 us; speedup 1.0000x reference)
//
#include <hip/hip_runtime.h>
#include <cstdint>

#define EPSV 1e-5f

typedef __bf16 bf16x8 __attribute__((ext_vector_type(8)));
typedef __bf16 bf16x2 __attribute__((ext_vector_type(2)));
typedef float  f32x4  __attribute__((ext_vector_type(4)));
typedef unsigned long long u64;

#define FILL_BLOCKS 512

// fp8 e4m3 (OCP) helpers — HW converts on gfx950.
__device__ __forceinline__ unsigned char f32_to_fp8(float x) {
    const int p = __builtin_amdgcn_cvt_pk_fp8_f32(x, x, 0, false);
    return (unsigned char)(p & 0xFF);
}

// ------------------------------------------------- deg/cnt/rank in one ----
// dc padded: ONE node per 128B line (stride 16 u64) -> ~16 RMWs/line instead
// of 256 (cross-XCD per-line serialization was the ~70us floor).
__global__ __launch_bounds__(256) void k_degacc(const int* __restrict__ ei,
                                                const float* __restrict__ ew,
                                                u64* __restrict__ dc,
                                                unsigned short* __restrict__ rank,
                                                int E) {
    const int e = blockIdx.x * 256 + threadIdx.x;
    if (e < E) {
        const int c = ei[E + e];
        const u64 pack = (1ull << 40) | (u64)(ew[e] * 16777216.0f);
        const u64 old = atomicAdd(&dc[(long)c << 4], pack);
        rank[e] = (unsigned short)(old >> 40);
    }
}

// ------------------------------- unpack: dinv + cnt + block-sum -----------
__global__ __launch_bounds__(256) void k_scanA(const u64* __restrict__ dc,
                                               float* __restrict__ dinv,
                                               int* __restrict__ cnt,
                                               int* __restrict__ bsum, int N) {
    __shared__ int ws[4];
    const int i = blockIdx.x * 256 + threadIdx.x;
    int v = 0;
    if (i < N) {
        const u64 p = dc[(long)i << 4];
        v = (int)(p >> 40);
        const float deg = 1.0f + (float)(p & 0xFFFFFFFFFFull) * (1.0f / 16777216.0f);
        dinv[i] = rsqrtf(deg);  // deg >= 1 always (self loop)
        cnt[i] = v;
    }
#pragma unroll
    for (int o = 32; o >= 1; o >>= 1) v += __shfl_xor(v, o);
    if ((threadIdx.x & 63) == 0) ws[threadIdx.x >> 6] = v;
    __syncthreads();
    if (threadIdx.x == 0) bsum[blockIdx.x] = ws[0] + ws[1] + ws[2] + ws[3];
}

// ---------------- merged scan: off[i] = prefix(bsum[<bid]) + local scan ---
__global__ __launch_bounds__(256) void k_scanB(const int* __restrict__ cnt,
                                               const int* __restrict__ bsum,
                                               int* __restrict__ off, int N) {
    __shared__ int pw[4];
    __shared__ int lw[4];
    __shared__ int sbase;
    const int bid = blockIdx.x;
    const int lane = threadIdx.x & 63, w = threadIdx.x >> 6;

    int pre = 0;
    for (int j = threadIdx.x; j < bid; j += 256) pre += bsum[j];
#pragma unroll
    for (int o = 32; o >= 1; o >>= 1) pre += __shfl_xor(pre, o);
    if (lane == 0) pw[w] = pre;
    __syncthreads();
    if (threadIdx.x == 0) sbase = pw[0] + pw[1] + pw[2] + pw[3];

    const int i = bid * 256 + threadIdx.x;
    const int v = (i < N) ? cnt[i] : 0;
    int s = v;
#pragma unroll
    for (int o = 1; o < 64; o <<= 1) {
        const int t = __shfl_up(s, o);
        if (lane >= o) s += t;
    }
    if (lane == 63) lw[w] = s;
    __syncthreads();
    int add = sbase;
    for (int k = 0; k < w; ++k) add += lw[k];
    if (i < N) off[i] = add + s - v;
}

// ----------------------------------------------------- W transpose+cvt ----
// Blob layout: WtB[k/8][c][8] bf16, i.e. elem = ((k>>3)*NOUT + c)*8 + (k&7).
__global__ __launch_bounds__(256) void k_wcvt(const float* __restrict__ W1,
                                              __bf16* __restrict__ Wt1,
                                              const float* __restrict__ W2,
                                              __bf16* __restrict__ Wt2) {
    const int idx = blockIdx.x * 256 + threadIdx.x;
    if (idx < 256 * 128) {                       // K=256, NOUT=128
        const int k = idx >> 7, c = idx & 127;
        Wt1[(((k >> 3) << 7) + c) * 8 + (k & 7)] = (__bf16)W1[idx];
    } else if (idx < 256 * 128 + 128 * 64) {     // K=128, NOUT=64
        const int j = idx - 256 * 128;
        const int k = j >> 6, c = j & 63;
        Wt2[(((k >> 3) << 6) + c) * 8 + (k & 7)] = (__bf16)W2[j];
    }
}

// ----------------------------------------------------------- MFMA GEMM ----
// H[N][NOUT] = X[N][K] @ W -> fp8 e4m3. WtB is blob layout (see k_wcvt).
// 4 waves x 32 rows = 128-row block tile; 2 row-fragments per wave.
template <int K, int NOUT, bool ABF16>
__device__ __forceinline__ void mm_body(int bid, int tid, const void* __restrict__ Xv,
                                        const __bf16* __restrict__ WtB,
                                        unsigned char* __restrict__ H, int N) {
    constexpr int NCB = NOUT / 16;
    constexpr int NKB = K / 32;
    const int w = tid >> 6, l = tid & 63;
    const int r0 = l & 15, kq = l >> 4;
    const long tb0 = (long)bid * 128 + w * 32;
    const long ar0 = (tb0 + r0) < N ? (tb0 + r0) : (long)N - 1;
    const long ar1 = (tb0 + 16 + r0) < N ? (tb0 + 16 + r0) : (long)N - 1;

    f32x4 acc[2][NCB];
#pragma unroll
    for (int rf = 0; rf < 2; ++rf)
#pragma unroll
        for (int cb = 0; cb < NCB; ++cb) acc[rf][cb] = (f32x4){0.f, 0.f, 0.f, 0.f};

#define LDA(kb, a0, a1)                                                          \
    {                                                                            \
        const int koff = (kb) * 32 + kq * 8;                                     \
        if constexpr (ABF16) {                                                   \
            a0 = *reinterpret_cast<const bf16x8*>((const __bf16*)Xv + ar0 * K + koff); \
            a1 = *reinterpret_cast<const bf16x8*>((const __bf16*)Xv + ar1 * K + koff); \
        } else {                                                                 \
            const float* p0 = (const float*)Xv + ar0 * K + koff;                 \
            const float* p1 = (const float*)Xv + ar1 * K + koff;                 \
            const float4 u0 = *reinterpret_cast<const float4*>(p0);              \
            const float4 u1 = *reinterpret_cast<const float4*>(p0 + 4);          \
            const float4 u2 = *reinterpret_cast<const float4*>(p1);              \
            const float4 u3 = *reinterpret_cast<const float4*>(p1 + 4);          \
            a0[0] = (__bf16)u0.x; a0[1] = (__bf16)u0.y; a0[2] = (__bf16)u0.z;    \
            a0[3] = (__bf16)u0.w; a0[4] = (__bf16)u1.x; a0[5] = (__bf16)u1.y;    \
            a0[6] = (__bf16)u1.z; a0[7] = (__bf16)u1.w;                          \
            a1[0] = (__bf16)u2.x; a1[1] = (__bf16)u2.y; a1[2] = (__bf16)u2.z;    \
            a1[3] = (__bf16)u2.w; a1[4] = (__bf16)u3.x; a1[5] = (__bf16)u3.y;    \
            a1[6] = (__bf16)u3.z; a1[7] = (__bf16)u3.w;                          \
        }                                                                        \
    }

#define LDB(kb, b)                                                               \
    {                                                                            \
        const __bf16* bp = WtB + (long)(((kb) * 4 + kq) * NOUT + r0) * 8;        \
        _Pragma("unroll") for (int cb = 0; cb < NCB; ++cb)                       \
            b[cb] = *reinterpret_cast<const bf16x8*>(bp + cb * 128);             \
    }

    bf16x8 aC0, aC1, aN0, aN1;
    bf16x8 bC[NCB], bN[NCB];
    LDA(0, aC0, aC1);
    LDB(0, bC);
#pragma unroll
    for (int kb = 0; kb < NKB; ++kb) {
        if (kb + 1 < NKB) {
            LDA(kb + 1, aN0, aN1);
            LDB(kb + 1, bN);
        }
#pragma unroll
        for (int cb = 0; cb < NCB; ++cb) {
            acc[0][cb] = __builtin_amdgcn_mfma_f32_16x16x32_bf16(aC0, bC[cb], acc[0][cb], 0, 0, 0);
            acc[1][cb] = __builtin_amdgcn_mfma_f32_16x16x32_bf16(aC1, bC[cb], acc[1][cb], 0, 0, 0);
        }
        aC0 = aN0; aC1 = aN1;
#pragma unroll
        for (int cb = 0; cb < NCB; ++cb) bC[cb] = bN[cb];
    }
#undef LDA
#undef LDB

    const int orow = kq * 4;
#pragma unroll
    for (int rf = 0; rf < 2; ++rf)
#pragma unroll
        for (int cb = 0; cb < NCB; ++cb)
#pragma unroll
            for (int r = 0; r < 4; ++r) {
                const long gr = tb0 + rf * 16 + orow + r;
                if (gr < N) H[gr * NOUT + cb * 16 + r0] = f32_to_fp8(acc[rf][cb][r]);
            }
}

// -------------------- fused: CSR fill (512 grid-stride blocks) || gemm1 ---
// Independent: fill is scatter-store bound, mm1 is stream/MFMA bound.
__global__ __launch_bounds__(256) void k_fuse(const int* __restrict__ ei,
                                              const float* __restrict__ ew,
                                              const float* __restrict__ dinv,
                                              const int* __restrict__ off,
                                              const unsigned short* __restrict__ rank,
                                              float2* __restrict__ ern, int E,
                                              const float* __restrict__ X,
                                              const __bf16* __restrict__ Wt1,
                                              unsigned char* __restrict__ H1, int N) {
    const int bid = blockIdx.x;
    if (bid < FILL_BLOCKS) {
        const int stride = FILL_BLOCKS * 256;
        for (int e = bid * 256 + threadIdx.x; e < E; e += stride) {
            const int r = ei[e];
            const int c = ei[E + e];
            const int p = off[c] + (int)rank[e];
            ern[p] = make_float2(__int_as_float(r), dinv[r] * ew[e] * dinv[c]);
        }
    } else {
        mm_body<256, 128, false>(bid - FILL_BLOCKS, threadIdx.x, X, Wt1, H1, N);
    }
}

__global__ __launch_bounds__(256) void k_mm2(const __bf16* __restrict__ X,
                                             const __bf16* __restrict__ Wt2,
                                             unsigned char* __restrict__ H, int N) {
    mm_body<128, 64, true>(blockIdx.x, threadIdx.x, X, Wt2, H, N);
}

// --------------------------------- gather + bias + ReLU + LayerNorm -------
// D=128 fp8 H: one wave per node, 2 fp8 per lane; writes bf16 ln1 out.
__global__ __launch_bounds__(256) void k_gat128(const unsigned char* __restrict__ H,
                                                const int* __restrict__ off,
                                                const int* __restrict__ cnt,
                                                const float2* __restrict__ ern,
                                                const float* __restrict__ dinv,
                                                const float* __restrict__ bias,
                                                const float* __restrict__ gm,
                                                const float* __restrict__ bt,
                                                __bf16* __restrict__ Out, int N) {
    const long wv = ((long)blockIdx.x * 256 + threadIdx.x) >> 6;
    const int lane = threadIdx.x & 63;
    if (wv >= N) return;
    const int s = off[wv];
    const int n = cnt[wv];
    const float d = dinv[wv];
    const unsigned short* Hp = reinterpret_cast<const unsigned short*>(H);

    const unsigned int h0 = Hp[wv * 64 + lane];
    float ax = __builtin_amdgcn_cvt_f32_fp8(h0, 0) * d * d;
    float ay = __builtin_amdgcn_cvt_f32_fp8(h0, 1) * d * d;

    int e = 0;
    for (; e + 8 <= n; e += 8) {
        float2 q[8];
#pragma unroll
        for (int j = 0; j < 8; ++j) q[j] = ern[s + e + j];
        unsigned int u[8];
#pragma unroll
        for (int j = 0; j < 8; ++j)
            u[j] = Hp[(long)__float_as_int(q[j].x) * 64 + lane];
#pragma unroll
        for (int j = 0; j < 8; ++j) {
            ax = fmaf(q[j].y, __builtin_amdgcn_cvt_f32_fp8(u[j], 0), ax);
            ay = fmaf(q[j].y, __builtin_amdgcn_cvt_f32_fp8(u[j], 1), ay);
        }
    }
    for (; e < n; ++e) {
        const float2 q = ern[s + e];
        const unsigned int u = Hp[(long)__float_as_int(q.x) * 64 + lane];
        ax = fmaf(q.y, __builtin_amdgcn_cvt_f32_fp8(u, 0), ax);
        ay = fmaf(q.y, __builtin_amdgcn_cvt_f32_fp8(u, 1), ay);
    }

    const float ux = fmaxf(ax + bias[2 * lane], 0.f);
    const float uy = fmaxf(ay + bias[2 * lane + 1], 0.f);
    float s1 = ux + uy, s2 = ux * ux + uy * uy;
#pragma unroll
    for (int o = 32; o >= 1; o >>= 1) {
        s1 += __shfl_xor(s1, o);
        s2 += __shfl_xor(s2, o);
    }
    const float mu = s1 * (1.f / 128.f);
    const float var = s2 * (1.f / 128.f) - mu * mu;
    const float rs = rsqrtf(var + EPSV);
    bf16x2 ob;
    ob[0] = (__bf16)((ux - mu) * rs * gm[2 * lane] + bt[2 * lane]);
    ob[1] = (__bf16)((uy - mu) * rs * gm[2 * lane + 1] + bt[2 * lane + 1]);
    reinterpret_cast<bf16x2*>(Out)[wv * 64 + lane] = ob;
}

// D=64 fp8 H: one wave per node, 1 fp8 per lane; writes bf16 LN output.
__global__ __launch_bounds__(256) void k_gat64(const unsigned char* __restrict__ H,
                                               const int* __restrict__ off,
                                               const int* __restrict__ cnt,
                                               const float2* __restrict__ ern,
                                               const float* __restrict__ dinv,
                                               const float* __restrict__ bias,
                                               const float* __restrict__ gm,
                                               const float* __restrict__ bt,
                                               __bf16* __restrict__ Out, int N) {
    const long wv = ((long)blockIdx.x * 256 + threadIdx.x) >> 6;
    const int lane = threadIdx.x & 63;
    if (wv >= N) return;
    const int s = off[wv];
    const int n = cnt[wv];
    const float d = dinv[wv];

    float acc = __builtin_amdgcn_cvt_f32_fp8((unsigned int)H[wv * 64 + lane], 0) * d * d;
    int e = 0;
    for (; e + 8 <= n; e += 8) {
        float2 q[8];
#pragma unroll
        for (int j = 0; j < 8; ++j) q[j] = ern[s + e + j];
        unsigned int u[8];
#pragma unroll
        for (int j = 0; j < 8; ++j)
            u[j] = H[(long)__float_as_int(q[j].x) * 64 + lane];
#pragma unroll
        for (int j = 0; j < 8; ++j)
            acc = fmaf(q[j].y, __builtin_amdgcn_cvt_f32_fp8(u[j], 0), acc);
    }
    for (; e < n; ++e) {
        const float2 q = ern[s + e];
        const unsigned int u = H[(long)__float_as_int(q.x) * 64 + lane];
        acc = fmaf(q.y, __builtin_amdgcn_cvt_f32_fp8(u, 0), acc);
    }

    const float u = fmaxf(acc + bias[lane], 0.f);
    float s1 = u, s2 = u * u;
#pragma unroll
    for (int o = 32; o >= 1; o >>= 1) {
        s1 += __shfl_xor(s1, o);
        s2 += __shfl_xor(s2, o);
    }
    const float mu = s1 * (1.f / 64.f);
    const float var = s2 * (1.f / 64.f) - mu * mu;
    const float rs = rsqrtf(var + EPSV);
    Out[wv * 64 + lane] = (__bf16)((u - mu) * rs * gm[lane] + bt[lane]);
}

// ---------------------------------------------------------------- pool ----
__global__ __launch_bounds__(256) void k_pool(const __bf16* __restrict__ C,
                                              const int* __restrict__ batch,
                                              float* __restrict__ pool,
                                              int N, int chunk) {
    const int wg = blockIdx.x * 4 + (threadIdx.x >> 6);
    const int lane = threadIdx.x & 63;
    long i = (long)wg * chunk;
    const long end = (i + chunk < (long)N) ? i + chunk : (long)N;
    if (i >= end) return;

    int cur = batch[i];
    float acc = 0.f;
    int cn = 0;
    while (i < end) {
        if (i + 8 <= end && batch[i + 7] == cur) {
            float v[8];
#pragma unroll
            for (int j = 0; j < 8; ++j) v[j] = (float)C[(i + j) * 64 + lane];
            acc += ((v[0] + v[1]) + (v[2] + v[3])) + ((v[4] + v[5]) + (v[6] + v[7]));
            cn += 8;
            i += 8;
            continue;
        }
        const int b = batch[i];
        if (b != cur) {
            unsafeAtomicAdd(&pool[cur * 64 + lane], acc);
            if (lane == 0) unsafeAtomicAdd(&pool[64 * 64 + cur], (float)cn);
            cur = b;
            acc = 0.f;
            cn = 0;
        }
        acc += (float)C[i * 64 + lane];
        ++cn;
        ++i;
    }
    unsafeAtomicAdd(&pool[cur * 64 + lane], acc);
    if (lane == 0) unsafeAtomicAdd(&pool[64 * 64 + cur], (float)cn);
}

__global__ __launch_bounds__(256) void k_final(const float* __restrict__ pool,
                                               float* __restrict__ out) {
    const int i = blockIdx.x * 256 + threadIdx.x;
    if (i < 4096) {
        const int g = i >> 6;
        const float cnt = fmaxf(pool[64 * 64 + g], 1.0f);
        const float v = pool[i] / cnt;
        out[i] = 1.f / (1.f + expf(-v));
    }
}

// -------------------------------------------------------------- launch ----
extern "C" void kernel_launch(void* const* d_in, const int* in_sizes, int n_in,
                              void* d_out, int out_size, void* d_ws, size_t ws_size,
                              hipStream_t stream) {
    const float* x   = (const float*)d_in[0];
    const int*   ei  = (const int*)d_in[1];
    const float* ew  = (const float*)d_in[2];
    const int*   bat = (const int*)d_in[3];
    const float* W1  = (const float*)d_in[4];
    const float* b1  = (const float*)d_in[5];
    const float* g1  = (const float*)d_in[6];
    const float* bt1 = (const float*)d_in[7];
    const float* W2  = (const float*)d_in[8];
    const float* b2  = (const float*)d_in[9];
    const float* g2  = (const float*)d_in[10];
    const float* bt2 = (const float*)d_in[11];
    const int N = in_sizes[3];
    const int E = in_sizes[2];
    const int NB = (N + 255) / 256;

    u64*    dc   = (u64*)d_ws;                              // [N*16] padded: 1 node / 128B line
    float*  pool = (float*)(dc + (long)N * 16);             // [64*64+64]
    float2* ern  = (float2*)(pool + 64 * 64 + 64);          // [E]
    unsigned char* Ah = (unsigned char*)(ern + E);          // [N*128] fp8 h1; reused h2 [N*64]
    __bf16* Bh   = (__bf16*)(Ah + (long)N * 128);           // [N*128] bf16 ln1 out
    __bf16* Cb   = Bh + (long)N * 128;                      // [N*64] bf16 ln2 out
    float*  dinv = (float*)(Cb + (long)N * 64);             // [N]
    int*    cnt  = (int*)(dinv + N);                        // [N]
    int*    off  = cnt + N;                                 // [N]
    int*    bsum = off + N;                                 // [NB] (padded)
    unsigned short* rank = (unsigned short*)(bsum + ((NB + 3) & ~3)); // [E]
    __bf16* Wt1  = (__bf16*)(rank + E);                     // [128*256] blob
    __bf16* Wt2  = Wt1 + 128 * 256;                         // [64*128] blob

    const int nbE = (E + 255) / 256;
    const int nbW = (int)(((long)N * 64 + 255) / 256);
    const int NBM = (N + 127) / 128;

    hipMemsetAsync(dc, 0, (size_t)N * 16 * 8 + (64 * 64 + 64) * 4, stream);
    k_wcvt<<<(256 * 128 + 128 * 64 + 255) / 256, 256, 0, stream>>>(W1, Wt1, W2, Wt2);

    k_degacc<<<nbE, 256, 0, stream>>>(ei, ew, dc, rank, E);
    k_scanA<<<NB, 256, 0, stream>>>(dc, dinv, cnt, bsum, N);
    k_scanB<<<NB, 256, 0, stream>>>(cnt, bsum, off, N);

    // fused: CSR fill (512 grid-stride blocks, first) || gemm1 (fp8 out)
    k_fuse<<<FILL_BLOCKS + NBM, 256, 0, stream>>>(ei, ew, dinv, off, rank, ern, E,
                                                  x, Wt1, Ah, N);

    // layer 1 aggregation + ReLU + LN
    k_gat128<<<nbW, 256, 0, stream>>>(Ah, off, cnt, ern, dinv, b1, g1, bt1, Bh, N);

    // layer 2: GCNConv(128->64) + ReLU + LN
    k_mm2<<<NBM, 256, 0, stream>>>(Bh, Wt2, Ah, N);
    k_gat64<<<nbW, 256, 0, stream>>>(Ah, off, cnt, ern, dinv, b2, g2, bt2, Cb, N);

    // global mean pool + sigmoid
    const int chunk = (N + 1023) / 1024;
    k_pool<<<256, 256, 0, stream>>>(Cb, bat, pool, N, chunk);
    k_final<<<16, 256, 0, stream>>>(pool, (float*)d_out);
}